// Round 8
// baseline (403.996 us; speedup 1.0000x reference)
//
#include <hip/hip_runtime.h>
#include <hip/hip_bf16.h>
#include <cmath>

#define Tt 2048
#define Cc 1024
#define Hh 16
#define HDd 64

#define KP 70  // sK/sV leading dim (shorts): 35 dwords, odd -> conflict-safe
#define PP 66  // sP leading dim (shorts): 33 dwords, odd -> conflict-safe

typedef __attribute__((ext_vector_type(8))) short short8;
typedef __attribute__((ext_vector_type(4))) float f32x4;

// async global->LDS, 16B per lane; lds base must be wave-uniform
#define ASYNC16(gp, lp)                                       \
    __builtin_amdgcn_global_load_lds(                         \
        (const __attribute__((address_space(1))) void*)(gp),  \
        (__attribute__((address_space(3))) void*)(lp), 16, 0, 0)

__device__ __forceinline__ unsigned short f32_bf16(float f) {
    unsigned u = __float_as_uint(f);
    u += 0x7FFF + ((u >> 16) & 1);
    return (unsigned short)(u >> 16);
}
// 2-op round-to-nearest (ties away) — fine for finite values
__device__ __forceinline__ unsigned short f32_bf16_rn(float f) {
    return (unsigned short)((__float_as_uint(f) + 0x8000u) >> 16);
}
__device__ __forceinline__ float fast_exp2(float x) {
#if __has_builtin(__builtin_amdgcn_exp2f)
    return __builtin_amdgcn_exp2f(x);
#else
    return exp2f(x);
#endif
}

// ---------------- fp32 -> bf16 convert: x + all 4 weights, one launch ----
__global__ __launch_bounds__(256) void cvt_all(
    const float* __restrict__ x, const float* __restrict__ a,
    const float* __restrict__ b, const float* __restrict__ c,
    const float* __restrict__ d, unsigned short* __restrict__ ox,
    unsigned short* __restrict__ oa, unsigned short* __restrict__ ob,
    unsigned short* __restrict__ oc, unsigned short* __restrict__ od) {
    const int id = blockIdx.x * 256 + threadIdx.x;
    const float* src; unsigned short* dst; int sub;
    if (id < 2097152) {
        src = x; dst = ox; sub = id;
    } else {
        const int wi = id - 2097152;
        const int which = wi >> 18;
        sub = wi & 262143;
        if (which == 0)      { src = a; dst = oa; }
        else if (which == 1) { src = b; dst = ob; }
        else if (which == 2) { src = c; dst = oc; }
        else                 { src = d; dst = od; }
    }
    float4 v = ((const float4*)src)[sub];
    ushort4 o;
    o.x = f32_bf16(v.x); o.y = f32_bf16(v.y);
    o.z = f32_bf16(v.z); o.w = f32_bf16(v.w);
    ((ushort4*)dst)[sub] = o;
}

// ---------------- fused QKV GEMM, single-barrier async dbuf --------------
__global__ __launch_bounds__(256) void gemm_qkv(const unsigned short* __restrict__ A,
                                                const unsigned short* __restrict__ Wcat,
                                                const float* __restrict__ bq,
                                                const float* __restrict__ bk,
                                                const float* __restrict__ bv,
                                                unsigned short* __restrict__ qout,
                                                unsigned short* __restrict__ kout,
                                                unsigned short* __restrict__ vout) {
    __shared__ unsigned short sA[2][128 * 32];
    __shared__ unsigned short sB[2][128 * 32];

    const int tid  = threadIdx.x;
    const int bm0  = blockIdx.y * 128;
    const int bn0  = blockIdx.x * 128;  // 0..3071
    const int wid  = tid >> 6;
    const int lane = tid & 63;
    const int quad = lane >> 4;
    const int lr   = lane & 15;
    const int wm   = (wid & 1) * 64;
    const int wn   = (wid >> 1) * 64;

    const int sr   = lane >> 2;
    const int scol = (lane & 3) * 8;
    const int row0 = wid * 16 + sr;
    const int row1 = 64 + wid * 16 + sr;
    const int lo0  = wid * 512;
    const int lo1  = (4 + wid) * 512;

    f32x4 acc[4][4];
    f32x4 zero = {0.f, 0.f, 0.f, 0.f};
#pragma unroll
    for (int i = 0; i < 4; i++)
#pragma unroll
        for (int j = 0; j < 4; j++) acc[i][j] = zero;

    ASYNC16(A    + (size_t)(bm0 + row0) * Cc + scol, sA[0] + lo0);
    ASYNC16(A    + (size_t)(bm0 + row1) * Cc + scol, sA[0] + lo1);
    ASYNC16(Wcat + (size_t)(bn0 + row0) * Cc + scol, sB[0] + lo0);
    ASYNC16(Wcat + (size_t)(bn0 + row1) * Cc + scol, sB[0] + lo1);
    __syncthreads();

    for (int kt = 0; kt < Cc / 32; ++kt) {
        const int cur = kt & 1, nxt = cur ^ 1;
        if (kt + 1 < Cc / 32) {
            const int kb = (kt + 1) * 32;
            ASYNC16(A    + (size_t)(bm0 + row0) * Cc + kb + scol, sA[nxt] + lo0);
            ASYNC16(A    + (size_t)(bm0 + row1) * Cc + kb + scol, sA[nxt] + lo1);
            ASYNC16(Wcat + (size_t)(bn0 + row0) * Cc + kb + scol, sB[nxt] + lo0);
            ASYNC16(Wcat + (size_t)(bn0 + row1) * Cc + kb + scol, sB[nxt] + lo1);
        }

        short8 af[4], bf[4];
#pragma unroll
        for (int i = 0; i < 4; i++)
            af[i] = *(const short8*)(sA[cur] + (wm + i * 16 + lr) * 32 + quad * 8);
#pragma unroll
        for (int j = 0; j < 4; j++)
            bf[j] = *(const short8*)(sB[cur] + (wn + j * 16 + lr) * 32 + quad * 8);
#pragma unroll
        for (int i = 0; i < 4; i++)
#pragma unroll
            for (int j = 0; j < 4; j++)
                acc[i][j] = __builtin_amdgcn_mfma_f32_16x16x32_bf16(af[i], bf[j], acc[i][j], 0, 0, 0);

        __syncthreads();
    }

    const int which = bn0 >> 10;  // 0=q 1=k 2=v
    const float* bias = (which == 0) ? bq : (which == 1) ? bk : bv;
    unsigned short* outp = (which == 0) ? qout : (which == 1) ? kout : vout;
    const float scale = (which == 0) ? 0.1803368801111204f : 1.0f;  // 0.125*log2e
    const bool vmode = (which == 2);
    const int nb = bn0 & 1023;

#pragma unroll
    for (int j = 0; j < 4; j++) {
        const int nl = nb + wn + j * 16 + lr;
        const float bvv = bias[nl];
        const int h = nl >> 6, hd = nl & 63;
#pragma unroll
        for (int i = 0; i < 4; i++) {
            const int m0 = bm0 + wm + i * 16 + quad * 4;
            const int b = m0 >> 11, t0 = m0 & 2047;
            if (vmode) {
                ushort4 pk;
                pk.x = f32_bf16_rn(acc[i][j][0] + bvv);
                pk.y = f32_bf16_rn(acc[i][j][1] + bvv);
                pk.z = f32_bf16_rn(acc[i][j][2] + bvv);
                pk.w = f32_bf16_rn(acc[i][j][3] + bvv);
                *(ushort4*)(outp + (((size_t)(b * Hh + h)) * HDd + hd) * Tt + t0) = pk;
            } else {
#pragma unroll
                for (int r = 0; r < 4; r++) {
                    const float val = (acc[i][j][r] + bvv) * scale;
                    outp[(((size_t)(b * Hh + h)) * Tt + t0 + r) * HDd + hd] =
                        f32_bf16_rn(val);
                }
            }
        }
    }
}

// ---------------- output projection GEMM: 128x64 tiles, fp32 out ---------
// grid (16,64) = 1024 blocks -> 4+ blocks/CU (was 512 = 2/CU, starved).
__global__ __launch_bounds__(256) void gemm_proj(const unsigned short* __restrict__ A,
                                                 const unsigned short* __restrict__ W,
                                                 const float* __restrict__ bias,
                                                 float* __restrict__ out) {
    __shared__ unsigned short sA[2][128 * 32];
    __shared__ unsigned short sB[2][64 * 32];

    const int tid  = threadIdx.x;
    const int bm0  = blockIdx.y * 128;
    const int bn0  = blockIdx.x * 64;
    const int wid  = tid >> 6;
    const int lane = tid & 63;
    const int quad = lane >> 4;
    const int lr   = lane & 15;
    const int wm   = (wid & 1) * 64;
    const int wn   = (wid >> 1) * 32;

    const int sr   = lane >> 2;
    const int scol = (lane & 3) * 8;
    const int row0 = wid * 16 + sr;          // A rows 0..63
    const int row1 = 64 + wid * 16 + sr;     // A rows 64..127; also B rows 0..63
    const int lo0  = wid * 512;
    const int lo1  = (4 + wid) * 512;

    f32x4 acc[4][2];
    f32x4 zero = {0.f, 0.f, 0.f, 0.f};
#pragma unroll
    for (int i = 0; i < 4; i++)
#pragma unroll
        for (int j = 0; j < 2; j++) acc[i][j] = zero;

    ASYNC16(A + (size_t)(bm0 + row0) * Cc + scol, sA[0] + lo0);
    ASYNC16(A + (size_t)(bm0 + row1) * Cc + scol, sA[0] + lo1);
    ASYNC16(W + (size_t)(bn0 + row0) * Cc + scol, sB[0] + lo0);
    __syncthreads();

    for (int kt = 0; kt < Cc / 32; ++kt) {
        const int cur = kt & 1, nxt = cur ^ 1;
        if (kt + 1 < Cc / 32) {
            const int kb = (kt + 1) * 32;
            ASYNC16(A + (size_t)(bm0 + row0) * Cc + kb + scol, sA[nxt] + lo0);
            ASYNC16(A + (size_t)(bm0 + row1) * Cc + kb + scol, sA[nxt] + lo1);
            ASYNC16(W + (size_t)(bn0 + row0) * Cc + kb + scol, sB[nxt] + lo0);
        }

        short8 af[4], bf[2];
#pragma unroll
        for (int i = 0; i < 4; i++)
            af[i] = *(const short8*)(sA[cur] + (wm + i * 16 + lr) * 32 + quad * 8);
#pragma unroll
        for (int j = 0; j < 2; j++)
            bf[j] = *(const short8*)(sB[cur] + (wn + j * 16 + lr) * 32 + quad * 8);
#pragma unroll
        for (int i = 0; i < 4; i++)
#pragma unroll
            for (int j = 0; j < 2; j++)
                acc[i][j] = __builtin_amdgcn_mfma_f32_16x16x32_bf16(af[i], bf[j], acc[i][j], 0, 0, 0);

        __syncthreads();
    }

#pragma unroll
    for (int j = 0; j < 2; j++) {
        const int n = bn0 + wn + j * 16 + lr;
        const float bvv = bias[n];
#pragma unroll
        for (int i = 0; i < 4; i++)
#pragma unroll
            for (int r = 0; r < 4; r++) {
                const int m = bm0 + wm + i * 16 + quad * 4 + r;
                out[(size_t)m * Cc + n] = acc[i][j][r] + bvv;
            }
    }
}

// ---------------- flash attention: 128-row Q, dbuf, 1D unpaired grid -----
// grid 1024: bh = flat&63 (same head per CU -> K/V L2-hot), qt = 15-(flat>>6)
// (heavy first; CU's 4 blocks span qt {a,a+4,a+8,a+12}). LDS 52.7 KB ->
// 3 blocks/CU. One barrier per tile (dbuf + register-relay prefetch).
// Unnormalized log2-domain softmax.
__global__ __launch_bounds__(256) void attn(const unsigned short* __restrict__ q,
                                            const unsigned short* __restrict__ k,
                                            const unsigned short* __restrict__ vt,
                                            unsigned short* __restrict__ y) {
    __shared__ unsigned short sK[2][64 * KP];
    __shared__ unsigned short sV[2][64 * KP];
    __shared__ unsigned short sP[4][2][16 * PP];  // [wave][strip]

    const int tid  = threadIdx.x;
    const int wid  = tid >> 6;
    const int lane = tid & 63;
    const int quad = lane >> 4;
    const int lr   = lane & 15;

    const int bh = blockIdx.x & 63;
    const int qt = 15 - (blockIdx.x >> 6);
    const size_t headq = (size_t)bh * Tt * HDd;
    const unsigned short* kg = k + headq;
    const unsigned short* vg = vt + headq;
    const int b = bh >> 4, h = bh & 15;

    const int rs0 = tid >> 3;
    const int es  = (tid & 7) * 8;

    f32x4 zero = {0.f, 0.f, 0.f, 0.f};

    const int qb = qt * 128;
    const int ntiles = 2 * qt + 2;

    short8 qf[2][2];
#pragma unroll
    for (int s = 0; s < 2; s++) {
        const unsigned short* qp =
            q + headq + (size_t)(qb + s * 64 + wid * 16 + lr) * HDd;
        qf[s][0] = *(const short8*)(qp + quad * 8);
        qf[s][1] = *(const short8*)(qp + 32 + quad * 8);
    }

    f32x4 o[2][4];
    float l_run[2][4];
#pragma unroll
    for (int s = 0; s < 2; s++)
#pragma unroll
        for (int i = 0; i < 4; i++) { o[s][i] = zero; l_run[s][i] = 0.f; }

    // tile 0 -> regs -> buf0
    uint4 ka0 = *(const uint4*)(kg + (size_t)(rs0)      * HDd + es);
    uint4 ka1 = *(const uint4*)(kg + (size_t)(rs0 + 32) * HDd + es);
    uint4 va0 = *(const uint4*)(vg + (size_t)(rs0)      * Tt + es);
    uint4 va1 = *(const uint4*)(vg + (size_t)(rs0 + 32) * Tt + es);
    *(uint4*)(sK[0] + rs0 * KP + es)        = ka0;
    *(uint4*)(sK[0] + (rs0 + 32) * KP + es) = ka1;
    *(uint4*)(sV[0] + rs0 * KP + es)        = va0;
    *(uint4*)(sV[0] + (rs0 + 32) * KP + es) = va1;
    __syncthreads();
    {
        const int kb2 = 64;
        ka0 = *(const uint4*)(kg + (size_t)(kb2 + rs0)      * HDd + es);
        ka1 = *(const uint4*)(kg + (size_t)(kb2 + rs0 + 32) * HDd + es);
        va0 = *(const uint4*)(vg + (size_t)(rs0)      * Tt + kb2 + es);
        va1 = *(const uint4*)(vg + (size_t)(rs0 + 32) * Tt + kb2 + es);
    }

    for (int kt = 0; kt < ntiles; ++kt) {
        const int cur = kt & 1, nxt = cur ^ 1;
        if (kt + 1 < ntiles) {
            *(uint4*)(sK[nxt] + rs0 * KP + es)        = ka0;
            *(uint4*)(sK[nxt] + (rs0 + 32) * KP + es) = ka1;
            *(uint4*)(sV[nxt] + rs0 * KP + es)        = va0;
            *(uint4*)(sV[nxt] + (rs0 + 32) * KP + es) = va1;
        }
        if (kt + 2 < ntiles) {
            const int kb2 = (kt + 2) * 64;
            ka0 = *(const uint4*)(kg + (size_t)(kb2 + rs0)      * HDd + es);
            ka1 = *(const uint4*)(kg + (size_t)(kb2 + rs0 + 32) * HDd + es);
            va0 = *(const uint4*)(vg + (size_t)(rs0)      * Tt + kb2 + es);
            va1 = *(const uint4*)(vg + (size_t)(rs0 + 32) * Tt + kb2 + es);
        }

        const unsigned short* bK = sK[cur];
        const unsigned short* bV = sV[cur];
        const int s_lo = (kt == ntiles - 1) ? 1 : 0;  // strip0 skips last tile

        // phase 1: QK^T for active strips
        f32x4 sc[2][4];
#pragma unroll
        for (int s = 0; s < 2; s++) {
            if (s < s_lo) continue;
#pragma unroll
            for (int nt = 0; nt < 4; nt++) {
                short8 b0 = *(const short8*)(bK + (nt * 16 + lr) * KP + quad * 8);
                short8 b1 = *(const short8*)(bK + (nt * 16 + lr) * KP + 32 + quad * 8);
                f32x4 a = zero;
                a = __builtin_amdgcn_mfma_f32_16x16x32_bf16(qf[s][0], b0, a, 0, 0, 0);
                a = __builtin_amdgcn_mfma_f32_16x16x32_bf16(qf[s][1], b1, a, 0, 0, 0);
                sc[s][nt] = a;
            }
        }

        // phase 2: mask diag, exp2, accumulate l, pack P to LDS
#pragma unroll
        for (int s = 0; s < 2; s++) {
            if (s < s_lo) continue;
            if (kt == ntiles - 2 + s) {
#pragma unroll
                for (int nt = 0; nt < 4; nt++)
#pragma unroll
                    for (int r = 0; r < 4; r++)
                        sc[s][nt][r] = (nt * 16 + lr <= wid * 16 + quad * 4 + r)
                                           ? sc[s][nt][r] : -INFINITY;
            }
            unsigned short* sPw = sP[wid][s];
#pragma unroll
            for (int nt = 0; nt < 4; nt++)
#pragma unroll
                for (int r = 0; r < 4; r++) {
                    const float p = fast_exp2(sc[s][nt][r]);
                    l_run[s][r] += p;
                    sPw[(quad * 4 + r) * PP + nt * 16 + lr] = f32_bf16_rn(p);
                }
        }

        // phase 3: P (A-layout) @ V
#pragma unroll
        for (int s = 0; s < 2; s++) {
            if (s < s_lo) continue;
            const unsigned short* sPw = sP[wid][s];
            short8 pa0 = *(const short8*)(sPw + lr * PP + quad * 8);
            short8 pa1 = *(const short8*)(sPw + lr * PP + 32 + quad * 8);
#pragma unroll
            for (int nt = 0; nt < 4; nt++) {
                short8 vb0 = *(const short8*)(bV + (nt * 16 + lr) * KP + quad * 8);
                short8 vb1 = *(const short8*)(bV + (nt * 16 + lr) * KP + 32 + quad * 8);
                o[s][nt] = __builtin_amdgcn_mfma_f32_16x16x32_bf16(pa0, vb0, o[s][nt], 0, 0, 0);
                o[s][nt] = __builtin_amdgcn_mfma_f32_16x16x32_bf16(pa1, vb1, o[s][nt], 0, 0, 0);
            }
        }

        __syncthreads();
    }

#pragma unroll
    for (int s = 0; s < 2; s++) {
#pragma unroll
        for (int r = 0; r < 4; r++) {
            float ls = l_run[s][r];
            ls += __shfl_xor(ls, 1);
            ls += __shfl_xor(ls, 2);
            ls += __shfl_xor(ls, 4);
            ls += __shfl_xor(ls, 8);
            const float inv = 1.0f / ls;
            const int t = qb + s * 64 + wid * 16 + quad * 4 + r;
#pragma unroll
            for (int nt = 0; nt < 4; nt++) {
                const int dim = nt * 16 + lr;
                y[((size_t)(b * Tt + t)) * Cc + h * HDd + dim] =
                    f32_bf16_rn(o[s][nt][r] * inv);
            }
        }
    }
}

// ---------------- launch ----------------
extern "C" void kernel_launch(void* const* d_in, const int* in_sizes, int n_in,
                              void* d_out, int out_size, void* d_ws, size_t ws_size,
                              hipStream_t stream) {
    const float* x  = (const float*)d_in[0];
    const float* Wk = (const float*)d_in[1];
    const float* bk = (const float*)d_in[2];
    const float* Wq = (const float*)d_in[3];
    const float* bq = (const float*)d_in[4];
    const float* Wv = (const float*)d_in[5];
    const float* bv = (const float*)d_in[6];
    const float* Wp = (const float*)d_in[7];
    const float* bp = (const float*)d_in[8];
    float* out = (float*)d_out;

    char* ws = (char*)d_ws;
    size_t off = 0;
    auto alloc = [&](size_t bytes) { char* p = ws + off; off += bytes; return p; };
    const size_t MK = (size_t)8192 * 1024;
    const size_t NK = (size_t)1024 * 1024;
    unsigned short* xb   = (unsigned short*)alloc(MK * 2);
    unsigned short* Wcat = (unsigned short*)alloc(3 * NK * 2);  // q|k|v contiguous
    unsigned short* Wqb  = Wcat;
    unsigned short* Wkb  = Wcat + NK;
    unsigned short* Wvb  = Wcat + 2 * NK;
    unsigned short* Wpb  = (unsigned short*)alloc(NK * 2);
    unsigned short* qh   = (unsigned short*)alloc(MK * 2);  // [B,H,T,HD], pre-scaled
    unsigned short* kh   = (unsigned short*)alloc(MK * 2);  // [B,H,T,HD]
    unsigned short* vth  = (unsigned short*)alloc(MK * 2);  // [B,H,HD,T]
    unsigned short* ya   = (unsigned short*)alloc(MK * 2);  // [B,T,C]

    cvt_all<<<12288, 256, 0, stream>>>(x, Wq, Wk, Wv, Wp, xb, Wqb, Wkb, Wvb, Wpb);

    gemm_qkv<<<dim3(24, 64), 256, 0, stream>>>(xb, Wcat, bq, bk, bv, qh, kh, vth);

    attn<<<1024, 256, 0, stream>>>(qh, kh, vth, ya);

    gemm_proj<<<dim3(16, 64), 256, 0, stream>>>(ya, Wpb, bp, out);
}

// Round 9
// 277.017 us; speedup vs baseline: 1.4584x; 1.4584x over previous
//
#include <hip/hip_runtime.h>
#include <hip/hip_bf16.h>
#include <cmath>

#define Tt 2048
#define Cc 1024
#define Hh 16
#define HDd 64

typedef __attribute__((ext_vector_type(8))) short short8;
typedef __attribute__((ext_vector_type(4))) float f32x4;

// async global->LDS, 16B per lane; lds base must be wave-uniform
#define ASYNC16(gp, lp)                                       \
    __builtin_amdgcn_global_load_lds(                         \
        (const __attribute__((address_space(1))) void*)(gp),  \
        (__attribute__((address_space(3))) void*)(lp), 16, 0, 0)

__device__ __forceinline__ unsigned short f32_bf16(float f) {
    unsigned u = __float_as_uint(f);
    u += 0x7FFF + ((u >> 16) & 1);
    return (unsigned short)(u >> 16);
}
// 2-op round-to-nearest (ties away) — fine for finite values
__device__ __forceinline__ unsigned short f32_bf16_rn(float f) {
    return (unsigned short)((__float_as_uint(f) + 0x8000u) >> 16);
}
__device__ __forceinline__ float fast_exp2(float x) {
#if __has_builtin(__builtin_amdgcn_exp2f)
    return __builtin_amdgcn_exp2f(x);
#else
    return exp2f(x);
#endif
}

// ---------------- fp32 -> bf16 convert: x + all 4 weights, one launch ----
__global__ __launch_bounds__(256) void cvt_all(
    const float* __restrict__ x, const float* __restrict__ a,
    const float* __restrict__ b, const float* __restrict__ c,
    const float* __restrict__ d, unsigned short* __restrict__ ox,
    unsigned short* __restrict__ oa, unsigned short* __restrict__ ob,
    unsigned short* __restrict__ oc, unsigned short* __restrict__ od) {
    const int id = blockIdx.x * 256 + threadIdx.x;
    const float* src; unsigned short* dst; int sub;
    if (id < 2097152) {
        src = x; dst = ox; sub = id;
    } else {
        const int wi = id - 2097152;
        const int which = wi >> 18;
        sub = wi & 262143;
        if (which == 0)      { src = a; dst = oa; }
        else if (which == 1) { src = b; dst = ob; }
        else if (which == 2) { src = c; dst = oc; }
        else                 { src = d; dst = od; }
    }
    float4 v = ((const float4*)src)[sub];
    ushort4 o;
    o.x = f32_bf16(v.x); o.y = f32_bf16(v.y);
    o.z = f32_bf16(v.z); o.w = f32_bf16(v.w);
    ((ushort4*)dst)[sub] = o;
}

// ---------------- fused QKV GEMM, single-barrier async dbuf --------------
__global__ __launch_bounds__(256) void gemm_qkv(const unsigned short* __restrict__ A,
                                                const unsigned short* __restrict__ Wcat,
                                                const float* __restrict__ bq,
                                                const float* __restrict__ bk,
                                                const float* __restrict__ bv,
                                                unsigned short* __restrict__ qout,
                                                unsigned short* __restrict__ kout,
                                                unsigned short* __restrict__ vout) {
    __shared__ unsigned short sA[2][128 * 32];
    __shared__ unsigned short sB[2][128 * 32];

    const int tid  = threadIdx.x;
    const int bm0  = blockIdx.y * 128;
    const int bn0  = blockIdx.x * 128;  // 0..3071
    const int wid  = tid >> 6;
    const int lane = tid & 63;
    const int quad = lane >> 4;
    const int lr   = lane & 15;
    const int wm   = (wid & 1) * 64;
    const int wn   = (wid >> 1) * 64;

    const int sr   = lane >> 2;
    const int scol = (lane & 3) * 8;
    const int row0 = wid * 16 + sr;
    const int row1 = 64 + wid * 16 + sr;
    const int lo0  = wid * 512;
    const int lo1  = (4 + wid) * 512;

    f32x4 acc[4][4];
    f32x4 zero = {0.f, 0.f, 0.f, 0.f};
#pragma unroll
    for (int i = 0; i < 4; i++)
#pragma unroll
        for (int j = 0; j < 4; j++) acc[i][j] = zero;

    ASYNC16(A    + (size_t)(bm0 + row0) * Cc + scol, sA[0] + lo0);
    ASYNC16(A    + (size_t)(bm0 + row1) * Cc + scol, sA[0] + lo1);
    ASYNC16(Wcat + (size_t)(bn0 + row0) * Cc + scol, sB[0] + lo0);
    ASYNC16(Wcat + (size_t)(bn0 + row1) * Cc + scol, sB[0] + lo1);
    __syncthreads();

    for (int kt = 0; kt < Cc / 32; ++kt) {
        const int cur = kt & 1, nxt = cur ^ 1;
        if (kt + 1 < Cc / 32) {
            const int kb = (kt + 1) * 32;
            ASYNC16(A    + (size_t)(bm0 + row0) * Cc + kb + scol, sA[nxt] + lo0);
            ASYNC16(A    + (size_t)(bm0 + row1) * Cc + kb + scol, sA[nxt] + lo1);
            ASYNC16(Wcat + (size_t)(bn0 + row0) * Cc + kb + scol, sB[nxt] + lo0);
            ASYNC16(Wcat + (size_t)(bn0 + row1) * Cc + kb + scol, sB[nxt] + lo1);
        }

        short8 af[4], bf[4];
#pragma unroll
        for (int i = 0; i < 4; i++)
            af[i] = *(const short8*)(sA[cur] + (wm + i * 16 + lr) * 32 + quad * 8);
#pragma unroll
        for (int j = 0; j < 4; j++)
            bf[j] = *(const short8*)(sB[cur] + (wn + j * 16 + lr) * 32 + quad * 8);
#pragma unroll
        for (int i = 0; i < 4; i++)
#pragma unroll
            for (int j = 0; j < 4; j++)
                acc[i][j] = __builtin_amdgcn_mfma_f32_16x16x32_bf16(af[i], bf[j], acc[i][j], 0, 0, 0);

        __syncthreads();
    }

    const int which = bn0 >> 10;  // 0=q 1=k 2=v
    const float* bias = (which == 0) ? bq : (which == 1) ? bk : bv;
    unsigned short* outp = (which == 0) ? qout : (which == 1) ? kout : vout;
    const float scale = (which == 0) ? 0.1803368801111204f : 1.0f;  // 0.125*log2e
    const bool vmode = (which == 2);
    const int nb = bn0 & 1023;

#pragma unroll
    for (int j = 0; j < 4; j++) {
        const int nl = nb + wn + j * 16 + lr;
        const float bvv = bias[nl];
        const int h = nl >> 6, hd = nl & 63;
#pragma unroll
        for (int i = 0; i < 4; i++) {
            const int m0 = bm0 + wm + i * 16 + quad * 4;
            const int b = m0 >> 11, t0 = m0 & 2047;
            if (vmode) {
                ushort4 pk;
                pk.x = f32_bf16_rn(acc[i][j][0] + bvv);
                pk.y = f32_bf16_rn(acc[i][j][1] + bvv);
                pk.z = f32_bf16_rn(acc[i][j][2] + bvv);
                pk.w = f32_bf16_rn(acc[i][j][3] + bvv);
                *(ushort4*)(outp + (((size_t)(b * Hh + h)) * HDd + hd) * Tt + t0) = pk;
            } else {
#pragma unroll
                for (int r = 0; r < 4; r++) {
                    const float val = (acc[i][j][r] + bvv) * scale;
                    outp[(((size_t)(b * Hh + h)) * Tt + t0 + r) * HDd + hd] =
                        f32_bf16_rn(val);
                }
            }
        }
    }
}

// ---------------- output projection GEMM: 128x64 tiles, fp32 out ---------
// grid (16,64) = 1024 blocks -> 4 blocks/CU (512 = 2/CU starved).
__global__ __launch_bounds__(256) void gemm_proj(const unsigned short* __restrict__ A,
                                                 const unsigned short* __restrict__ W,
                                                 const float* __restrict__ bias,
                                                 float* __restrict__ out) {
    __shared__ unsigned short sA[2][128 * 32];
    __shared__ unsigned short sB[2][64 * 32];

    const int tid  = threadIdx.x;
    const int bm0  = blockIdx.y * 128;
    const int bn0  = blockIdx.x * 64;
    const int wid  = tid >> 6;
    const int lane = tid & 63;
    const int quad = lane >> 4;
    const int lr   = lane & 15;
    const int wm   = (wid & 1) * 64;
    const int wn   = (wid >> 1) * 32;

    const int sr   = lane >> 2;
    const int scol = (lane & 3) * 8;
    const int row0 = wid * 16 + sr;          // A rows 0..63
    const int row1 = 64 + wid * 16 + sr;     // A rows 64..127; also B rows 0..63
    const int lo0  = wid * 512;
    const int lo1  = (4 + wid) * 512;

    f32x4 acc[4][2];
    f32x4 zero = {0.f, 0.f, 0.f, 0.f};
#pragma unroll
    for (int i = 0; i < 4; i++)
#pragma unroll
        for (int j = 0; j < 2; j++) acc[i][j] = zero;

    ASYNC16(A + (size_t)(bm0 + row0) * Cc + scol, sA[0] + lo0);
    ASYNC16(A + (size_t)(bm0 + row1) * Cc + scol, sA[0] + lo1);
    ASYNC16(W + (size_t)(bn0 + row0) * Cc + scol, sB[0] + lo0);
    __syncthreads();

    for (int kt = 0; kt < Cc / 32; ++kt) {
        const int cur = kt & 1, nxt = cur ^ 1;
        if (kt + 1 < Cc / 32) {
            const int kb = (kt + 1) * 32;
            ASYNC16(A + (size_t)(bm0 + row0) * Cc + kb + scol, sA[nxt] + lo0);
            ASYNC16(A + (size_t)(bm0 + row1) * Cc + kb + scol, sA[nxt] + lo1);
            ASYNC16(W + (size_t)(bn0 + row0) * Cc + kb + scol, sB[nxt] + lo0);
        }

        short8 af[4], bf[2];
#pragma unroll
        for (int i = 0; i < 4; i++)
            af[i] = *(const short8*)(sA[cur] + (wm + i * 16 + lr) * 32 + quad * 8);
#pragma unroll
        for (int j = 0; j < 2; j++)
            bf[j] = *(const short8*)(sB[cur] + (wn + j * 16 + lr) * 32 + quad * 8);
#pragma unroll
        for (int i = 0; i < 4; i++)
#pragma unroll
            for (int j = 0; j < 2; j++)
                acc[i][j] = __builtin_amdgcn_mfma_f32_16x16x32_bf16(af[i], bf[j], acc[i][j], 0, 0, 0);

        __syncthreads();
    }

#pragma unroll
    for (int j = 0; j < 2; j++) {
        const int n = bn0 + wn + j * 16 + lr;
        const float bvv = bias[n];
#pragma unroll
        for (int i = 0; i < 4; i++)
#pragma unroll
            for (int r = 0; r < 4; r++) {
                const int m = bm0 + wm + i * 16 + quad * 4 + r;
                out[(size_t)m * Cc + n] = acc[i][j][r] + bvv;
            }
    }
}

// ---------------- flash attention: round-4-proven config -----------------
// grid (8,64): block handles Q-blocks qt=x and qt=15-x -> exactly 34
// tile-iters per block (perfect balance). K/V double-buffered in LDS with
// register-relay prefetch: ONE __syncthreads per tile. Per-strip sP.
// LDS leading dims are 72 shorts = 144 B (multiple of 16 B: b128-aligned;
// 70 is NOT and cost 2.7x in round 8). Unnormalized log2-domain softmax.
__global__ __launch_bounds__(256) void attn(const unsigned short* __restrict__ q,
                                            const unsigned short* __restrict__ k,
                                            const unsigned short* __restrict__ vt,
                                            unsigned short* __restrict__ y) {
    __shared__ unsigned short sK[2][64 * 72];
    __shared__ unsigned short sV[2][64 * 72];
    __shared__ unsigned short sP[4][2][16 * 72];  // [wave][strip]

    const int tid  = threadIdx.x;
    const int wid  = tid >> 6;
    const int lane = tid & 63;
    const int quad = lane >> 4;
    const int lr   = lane & 15;

    const int bh = blockIdx.y;
    const size_t headq = (size_t)bh * Tt * HDd;
    const unsigned short* kg = k + headq;
    const unsigned short* vg = vt + headq;
    const int b = bh >> 4, h = bh & 15;

    const int rs0 = tid >> 3;
    const int es  = (tid & 7) * 8;

    f32x4 zero = {0.f, 0.f, 0.f, 0.f};

    for (int pass = 0; pass < 2; ++pass) {
        const int qt = pass ? (15 - blockIdx.x) : blockIdx.x;
        const int qb = qt * 128;
        const int ntiles = 2 * qt + 2;

        short8 qf[2][2];
#pragma unroll
        for (int s = 0; s < 2; s++) {
            const unsigned short* qp =
                q + headq + (size_t)(qb + s * 64 + wid * 16 + lr) * HDd;
            qf[s][0] = *(const short8*)(qp + quad * 8);
            qf[s][1] = *(const short8*)(qp + 32 + quad * 8);
        }

        f32x4 o[2][4];
        float l_run[2][4];
#pragma unroll
        for (int s = 0; s < 2; s++)
#pragma unroll
            for (int i = 0; i < 4; i++) { o[s][i] = zero; l_run[s][i] = 0.f; }

        // tile 0 -> regs -> buf0
        uint4 ka0 = *(const uint4*)(kg + (size_t)(rs0)      * HDd + es);
        uint4 ka1 = *(const uint4*)(kg + (size_t)(rs0 + 32) * HDd + es);
        uint4 va0 = *(const uint4*)(vg + (size_t)(rs0)      * Tt + es);
        uint4 va1 = *(const uint4*)(vg + (size_t)(rs0 + 32) * Tt + es);
        *(uint4*)(sK[0] + rs0 * 72 + es)        = ka0;
        *(uint4*)(sK[0] + (rs0 + 32) * 72 + es) = ka1;
        *(uint4*)(sV[0] + rs0 * 72 + es)        = va0;
        *(uint4*)(sV[0] + (rs0 + 32) * 72 + es) = va1;
        __syncthreads();
        {
            const int kb2 = 64;
            ka0 = *(const uint4*)(kg + (size_t)(kb2 + rs0)      * HDd + es);
            ka1 = *(const uint4*)(kg + (size_t)(kb2 + rs0 + 32) * HDd + es);
            va0 = *(const uint4*)(vg + (size_t)(rs0)      * Tt + kb2 + es);
            va1 = *(const uint4*)(vg + (size_t)(rs0 + 32) * Tt + kb2 + es);
        }

        for (int kt = 0; kt < ntiles; ++kt) {
            const int cur = kt & 1, nxt = cur ^ 1;
            if (kt + 1 < ntiles) {
                *(uint4*)(sK[nxt] + rs0 * 72 + es)        = ka0;
                *(uint4*)(sK[nxt] + (rs0 + 32) * 72 + es) = ka1;
                *(uint4*)(sV[nxt] + rs0 * 72 + es)        = va0;
                *(uint4*)(sV[nxt] + (rs0 + 32) * 72 + es) = va1;
            }
            if (kt + 2 < ntiles) {
                const int kb2 = (kt + 2) * 64;
                ka0 = *(const uint4*)(kg + (size_t)(kb2 + rs0)      * HDd + es);
                ka1 = *(const uint4*)(kg + (size_t)(kb2 + rs0 + 32) * HDd + es);
                va0 = *(const uint4*)(vg + (size_t)(rs0)      * Tt + kb2 + es);
                va1 = *(const uint4*)(vg + (size_t)(rs0 + 32) * Tt + kb2 + es);
            }

            const unsigned short* bK = sK[cur];
            const unsigned short* bV = sV[cur];
            const int s_lo = (kt == ntiles - 1) ? 1 : 0;  // strip0 skips last tile

            // phase 1: QK^T for active strips
            f32x4 sc[2][4];
#pragma unroll
            for (int s = 0; s < 2; s++) {
                if (s < s_lo) continue;
#pragma unroll
                for (int nt = 0; nt < 4; nt++) {
                    short8 b0 = *(const short8*)(bK + (nt * 16 + lr) * 72 + quad * 8);
                    short8 b1 = *(const short8*)(bK + (nt * 16 + lr) * 72 + 32 + quad * 8);
                    f32x4 a = zero;
                    a = __builtin_amdgcn_mfma_f32_16x16x32_bf16(qf[s][0], b0, a, 0, 0, 0);
                    a = __builtin_amdgcn_mfma_f32_16x16x32_bf16(qf[s][1], b1, a, 0, 0, 0);
                    sc[s][nt] = a;
                }
            }

            // phase 2: mask diag, exp2, accumulate l, pack P to LDS
#pragma unroll
            for (int s = 0; s < 2; s++) {
                if (s < s_lo) continue;
                if (kt == ntiles - 2 + s) {
#pragma unroll
                    for (int nt = 0; nt < 4; nt++)
#pragma unroll
                        for (int r = 0; r < 4; r++)
                            sc[s][nt][r] = (nt * 16 + lr <= wid * 16 + quad * 4 + r)
                                               ? sc[s][nt][r] : -INFINITY;
                }
                unsigned short* sPw = sP[wid][s];
#pragma unroll
                for (int nt = 0; nt < 4; nt++)
#pragma unroll
                    for (int r = 0; r < 4; r++) {
                        const float p = fast_exp2(sc[s][nt][r]);
                        l_run[s][r] += p;
                        sPw[(quad * 4 + r) * 72 + nt * 16 + lr] = f32_bf16_rn(p);
                    }
            }

            // phase 3: P (A-layout) @ V
#pragma unroll
            for (int s = 0; s < 2; s++) {
                if (s < s_lo) continue;
                const unsigned short* sPw = sP[wid][s];
                short8 pa0 = *(const short8*)(sPw + lr * 72 + quad * 8);
                short8 pa1 = *(const short8*)(sPw + lr * 72 + 32 + quad * 8);
#pragma unroll
                for (int nt = 0; nt < 4; nt++) {
                    short8 vb0 = *(const short8*)(bV + (nt * 16 + lr) * 72 + quad * 8);
                    short8 vb1 = *(const short8*)(bV + (nt * 16 + lr) * 72 + 32 + quad * 8);
                    o[s][nt] = __builtin_amdgcn_mfma_f32_16x16x32_bf16(pa0, vb0, o[s][nt], 0, 0, 0);
                    o[s][nt] = __builtin_amdgcn_mfma_f32_16x16x32_bf16(pa1, vb1, o[s][nt], 0, 0, 0);
                }
            }

            __syncthreads();
        }

#pragma unroll
        for (int s = 0; s < 2; s++) {
#pragma unroll
            for (int r = 0; r < 4; r++) {
                float ls = l_run[s][r];
                ls += __shfl_xor(ls, 1);
                ls += __shfl_xor(ls, 2);
                ls += __shfl_xor(ls, 4);
                ls += __shfl_xor(ls, 8);
                const float inv = 1.0f / ls;
                const int t = qb + s * 64 + wid * 16 + quad * 4 + r;
#pragma unroll
                for (int nt = 0; nt < 4; nt++) {
                    const int dim = nt * 16 + lr;
                    y[((size_t)(b * Tt + t)) * Cc + h * HDd + dim] =
                        f32_bf16_rn(o[s][nt][r] * inv);
                }
            }
        }
    }
}

// ---------------- launch ----------------
extern "C" void kernel_launch(void* const* d_in, const int* in_sizes, int n_in,
                              void* d_out, int out_size, void* d_ws, size_t ws_size,
                              hipStream_t stream) {
    const float* x  = (const float*)d_in[0];
    const float* Wk = (const float*)d_in[1];
    const float* bk = (const float*)d_in[2];
    const float* Wq = (const float*)d_in[3];
    const float* bq = (const float*)d_in[4];
    const float* Wv = (const float*)d_in[5];
    const float* bv = (const float*)d_in[6];
    const float* Wp = (const float*)d_in[7];
    const float* bp = (const float*)d_in[8];
    float* out = (float*)d_out;

    char* ws = (char*)d_ws;
    size_t off = 0;
    auto alloc = [&](size_t bytes) { char* p = ws + off; off += bytes; return p; };
    const size_t MK = (size_t)8192 * 1024;
    const size_t NK = (size_t)1024 * 1024;
    unsigned short* xb   = (unsigned short*)alloc(MK * 2);
    unsigned short* Wcat = (unsigned short*)alloc(3 * NK * 2);  // q|k|v contiguous
    unsigned short* Wqb  = Wcat;
    unsigned short* Wkb  = Wcat + NK;
    unsigned short* Wvb  = Wcat + 2 * NK;
    unsigned short* Wpb  = (unsigned short*)alloc(NK * 2);
    unsigned short* qh   = (unsigned short*)alloc(MK * 2);  // [B,H,T,HD], pre-scaled
    unsigned short* kh   = (unsigned short*)alloc(MK * 2);  // [B,H,T,HD]
    unsigned short* vth  = (unsigned short*)alloc(MK * 2);  // [B,H,HD,T]
    unsigned short* ya   = (unsigned short*)alloc(MK * 2);  // [B,T,C]

    cvt_all<<<12288, 256, 0, stream>>>(x, Wq, Wk, Wv, Wp, xb, Wqb, Wkb, Wvb, Wpb);

    gemm_qkv<<<dim3(24, 64), 256, 0, stream>>>(xb, Wcat, bq, bk, bv, qh, kh, vth);

    attn<<<dim3(8, 64), 256, 0, stream>>>(qh, kh, vth, ya);

    gemm_proj<<<dim3(16, 64), 256, 0, stream>>>(ya, Wpb, bp, out);
}